// Round 2
// baseline (23.420 us; speedup 1.0000x reference)
//
#include <hip/hip_runtime.h>
#include <math.h>

// Problem constants (hardcoded in reference)
#define B_  15
#define TO_ 10   // T_OUT
#define TI_ 10   // T_IN
#define H_  4
#define G_  16   // 4*H
#define D_  512

__device__ __forceinline__ float sigf(float x) { return 1.0f / (1.0f + expf(-x)); }

// ---------------------------------------------------------------------------
// ONE kernel, ONE block per batch element. Everything (input projection,
// LSTM scan, buggy attention) is independent per b, so no inter-block sync
// and no second dispatch are needed.
// ---------------------------------------------------------------------------
__global__ void __launch_bounds__(256) fused_kernel(
        const float* __restrict__ x,     // [B,TO,D]
        const float* __restrict__ h0,    // [1,B,H]
        const float* __restrict__ c0,    // [1,B,H]
        const float* __restrict__ enc,   // [B,TI,H]
        const float* __restrict__ Wih,   // [G,D]
        const float* __restrict__ Whh,   // [G,H]
        const float* __restrict__ b_ih,  // [G]
        const float* __restrict__ b_hh,  // [G]
        float* __restrict__ out) {       // [B,TO,2H]
    const int b   = blockIdx.x;
    const int tid = threadIdx.x;

    __shared__ float  xg_s[TO_][G_];
    __shared__ float  att_s[TO_][H_];
    __shared__ float  enc_s[TI_][H_];
    __shared__ float  ex_s[TO_][TI_];
    __shared__ double s10_s[TO_];

    // Wave 0 prefetches its LSTM params into registers; the loads' latency
    // hides under the phase-1 dot products.
    float wv0 = 0.f, wv1 = 0.f, wv2 = 0.f, wv3 = 0.f, hreg = 0.f, creg = 0.f;
    if (tid < 64) {
        int g = tid & 15, j = tid & 3;
        wv0 = Whh[g * 4 + 0];
        wv1 = Whh[g * 4 + 1];
        wv2 = Whh[g * 4 + 2];
        wv3 = Whh[g * 4 + 3];
        hreg = h0[b * H_ + j];
        creg = c0[b * H_ + j];
    }

    // ---- phase 1: xg[t][g] = x[b,t,:]·Wih[g,:] + b_ih[g] + b_hh[g] ----
    if (tid < TO_ * G_) {
        int t = tid >> 4, g = tid & 15;
        const float4* xr = (const float4*)(x + (size_t)(b * TO_ + t) * D_);
        const float4* wr = (const float4*)(Wih + (size_t)g * D_);
        float s = 0.f;
#pragma unroll 8
        for (int d = 0; d < D_ / 4; ++d) {
            float4 a = xr[d], w = wr[d];
            s += a.x * w.x + a.y * w.y + a.z * w.z + a.w * w.w;
        }
        xg_s[t][g] = s + b_ih[g] + b_hh[g];
    } else if (tid >= 160 && tid < 160 + TI_ * H_) {
        int i = tid - 160;
        ((float*)enc_s)[i] = enc[b * TI_ * H_ + i];
    }
    __syncthreads();

    // ---- phase 2: LSTM scan, wave 0 only, zero barriers inside the loop.
    // All 64 lanes run replicated copies (lane&15 = gate); canonical values
    // live in lanes 0..15 and are read via shuffles.
    if (tid < 64) {
        int g = tid & 15, j = tid & 3;
        for (int t = 0; t < TO_; ++t) {
            float v = xg_s[t][g];
            float h0v = __shfl(hreg, 0), h1v = __shfl(hreg, 1),
                  h2v = __shfl(hreg, 2), h3v = __shfl(hreg, 3);
            v += h0v * wv0 + h1v * wv1 + h2v * wv2 + h3v * wv3;
            float act = (g >= 8 && g < 12) ? tanhf(v) : sigf(v);
            float ai = __shfl(act, j),      af = __shfl(act, j + 4),
                  ag = __shfl(act, j + 8),  ao = __shfl(act, j + 12);
            creg = af * creg + ai * ag;
            hreg = ao * tanhf(creg);
            if (tid < 4) att_s[t][tid] = hreg;
        }
    }
    __syncthreads();

    // ---- phase 3: ex[l][k] = exp(<att[l], enc[k]>) ----
    if (tid < TO_ * TI_) {
        int l = tid / TI_, k = tid % TI_;
        float d = 0.f;
#pragma unroll
        for (int j = 0; j < H_; ++j) d += att_s[l][j] * enc_s[k][j];
        ex_s[l][k] = expf(d);
    }
    __syncthreads();

    // ---- row sums -> s^10 (double: s^10 can overflow fp32) ----
    if (tid < TO_) {
        float s = 0.f;
#pragma unroll
        for (int k = 0; k < TI_; ++k) s += ex_s[tid][k];
        double sd = (double)s, p = 1.0;
#pragma unroll
        for (int q = 0; q < TI_; ++q) p *= sd;
        s10_s[tid] = p;
    }
    __syncthreads();

    // ---- cumprod over l per column k; the faithful bug: only k==TI_-1 is
    // divided (by s^TI_), folded into the cumprod. In-place like reference.
    if (tid < TI_) {
        int k = tid;
        float prod = 1.f;
#pragma unroll
        for (int l = 0; l < TO_; ++l) {
            float w = ex_s[l][k];
            if (k == TI_ - 1) w = (float)((double)w / s10_s[l]);
            prod *= w;
            ex_s[l][k] = prod;
        }
    }
    __syncthreads();

    // ---- cn[l][d] = sum_k cumw[l][k]*enc[k][d]; out = concat([cn, att]) ----
    if (tid < TO_ * H_) {
        int l = tid / H_, d = tid % H_;
        float cn = 0.f;
#pragma unroll
        for (int k = 0; k < TI_; ++k) cn += ex_s[l][k] * enc_s[k][d];
        float* o = out + (size_t)(b * TO_ + l) * (2 * H_);
        o[d]      = cn;
        o[H_ + d] = att_s[l][d];
    }
}

extern "C" void kernel_launch(void* const* d_in, const int* in_sizes, int n_in,
                              void* d_out, int out_size, void* d_ws, size_t ws_size,
                              hipStream_t stream) {
    const float* x    = (const float*)d_in[0];  // [15,10,512]
    const float* h0   = (const float*)d_in[1];  // [1,15,4]
    const float* c0   = (const float*)d_in[2];  // [1,15,4]
    const float* enc  = (const float*)d_in[3];  // [15,10,4]
    const float* W_ih = (const float*)d_in[4];  // [16,512]
    const float* W_hh = (const float*)d_in[5];  // [16,4]
    const float* b_ih = (const float*)d_in[6];  // [16]
    const float* b_hh = (const float*)d_in[7];  // [16]
    float*       out  = (float*)d_out;          // [15,10,8]

    fused_kernel<<<B_, 256, 0, stream>>>(x, h0, c0, enc, W_ih, W_hh, b_ih, b_hh, out);
}

// Round 3
// 16.763 us; speedup vs baseline: 1.3971x; 1.3971x over previous
//
#include <hip/hip_runtime.h>
#include <math.h>

// Problem constants (hardcoded in reference)
#define B_  15
#define TO_ 10   // T_OUT
#define TI_ 10   // T_IN
#define H_  4
#define G_  16   // 4*H
#define D_  512

// ---------------------------------------------------------------------------
// ONE kernel, ONE block per batch element (all phases are per-b independent).
// Phase 1 projection: 16 lanes per dot product, wave-uniform (t, g-quad) so
// every global load instruction is 1-4 coalesced 256B segments (vs 16
// scattered rows in the previous round — that was the regression).
// ---------------------------------------------------------------------------
__global__ void __launch_bounds__(256) fused_kernel(
        const float* __restrict__ x,     // [B,TO,D]
        const float* __restrict__ h0,    // [1,B,H]
        const float* __restrict__ c0,    // [1,B,H]
        const float* __restrict__ enc,   // [B,TI,H]
        const float* __restrict__ Wih,   // [G,D]
        const float* __restrict__ Whh,   // [G,H]
        const float* __restrict__ b_ih,  // [G]
        const float* __restrict__ b_hh,  // [G]
        float* __restrict__ out) {       // [B,TO,2H]
    const int b    = blockIdx.x;
    const int tid  = threadIdx.x;
    const int wave = tid >> 6;
    const int lane = tid & 63;
    const int sub  = lane & 15;   // lane within 16-group
    const int grp  = lane >> 4;   // which 16-group (0..3)

    __shared__ float  xg_s[TO_][G_];
    __shared__ float  att_s[TO_][H_];
    __shared__ float  enc_s[TI_][H_];
    __shared__ float  ex_s[TO_][TI_];
    __shared__ double s10_s[TO_];

    // Wave 0 prefetches LSTM params into registers; latency hides under
    // phase 1's dot products.
    float wv0 = 0.f, wv1 = 0.f, wv2 = 0.f, wv3 = 0.f, hreg = 0.f, creg = 0.f;
    if (wave == 0) {
        int g = lane & 15, j = lane & 3;
        wv0  = Whh[g * 4 + 0];
        wv1  = Whh[g * 4 + 1];
        wv2  = Whh[g * 4 + 2];
        wv3  = Whh[g * 4 + 3];
        hreg = h0[b * H_ + j];
        creg = c0[b * H_ + j];
    }

    // ---- phase 1: xg[t][g] = x[b,t,:]·Wih[g,:] + b_ih[g] + b_hh[g] ----
    // 160 dots = 40 quads; each wave does 10 quads; per quad, 4 dots
    // (g = q*4 + grp) with 16 lanes each.
#pragma unroll
    for (int it = 0; it < 10; ++it) {
        int quad = wave * 10 + it;          // wave-uniform
        int t    = quad >> 2;
        int q    = quad & 3;
        int g    = q * 4 + grp;
        const float4* xr = (const float4*)(x   + (size_t)(b * TO_ + t) * D_);
        const float4* wr = (const float4*)(Wih + (size_t)g * D_);
        float s0 = 0.f, s1 = 0.f;
#pragma unroll
        for (int j = 0; j < 8; j += 2) {
            float4 a0 = xr[sub + j * 16],       w0 = wr[sub + j * 16];
            float4 a1 = xr[sub + (j + 1) * 16], w1 = wr[sub + (j + 1) * 16];
            s0 += a0.x * w0.x + a0.y * w0.y + a0.z * w0.z + a0.w * w0.w;
            s1 += a1.x * w1.x + a1.y * w1.y + a1.z * w1.z + a1.w * w1.w;
        }
        float s = s0 + s1;
        s += __shfl_xor(s, 1);
        s += __shfl_xor(s, 2);
        s += __shfl_xor(s, 4);
        s += __shfl_xor(s, 8);
        if (sub == 0) xg_s[t][g] = s + b_ih[g] + b_hh[g];
    }
    __syncthreads();

    // ---- phase 2: wave 0 runs the LSTM scan (shuffle-only, no barriers);
    //      wave 1 concurrently stages enc into LDS.
    if (wave == 1 && lane < TI_ * H_)
        ((float*)enc_s)[lane] = enc[b * TI_ * H_ + lane];
    if (wave == 0) {
        int g = lane & 15, j = lane & 3;
        // uniform activation: a=2 -> tanh(v)=2/(1+e^-2v)-1 ; a=1 -> sigmoid
        float a   = (g >= 8 && g < 12) ? 2.f : 1.f;
        float am1 = a - 1.f;
        for (int t = 0; t < TO_; ++t) {
            float v = xg_s[t][g];
            v += __shfl(hreg, 0) * wv0 + __shfl(hreg, 1) * wv1 +
                 __shfl(hreg, 2) * wv2 + __shfl(hreg, 3) * wv3;
            float act = a / (1.f + __expf(-a * v)) - am1;
            float ai = __shfl(act, j),     af = __shfl(act, j + 4),
                  ag = __shfl(act, j + 8), ao = __shfl(act, j + 12);
            creg = af * creg + ai * ag;
            float th = 2.f / (1.f + __expf(-2.f * creg)) - 1.f;
            hreg = ao * th;
            if (lane < 4) att_s[t][lane] = hreg;
        }
    }
    __syncthreads();

    // ---- phase 3: ex[l][k] = exp(<att[l], enc[k]>) ----
    if (tid < TO_ * TI_) {
        int l = tid / TI_, k = tid % TI_;
        float d = 0.f;
#pragma unroll
        for (int j = 0; j < H_; ++j) d += att_s[l][j] * enc_s[k][j];
        ex_s[l][k] = __expf(d);
    }
    __syncthreads();

    // ---- phase 4: row sums -> s^10 in double (s^10 overflows fp32) ----
    if (tid < TO_) {
        float s = 0.f;
#pragma unroll
        for (int k = 0; k < TI_; ++k) s += ex_s[tid][k];
        double sd = (double)s, p = 1.0;
#pragma unroll
        for (int q = 0; q < TI_; ++q) p *= sd;
        s10_s[tid] = p;
    }
    __syncthreads();

    // ---- phase 5: cumprod over l per column k; faithful bug: only the last
    //      key column is divided by s^TI_, folded into the cumprod.
    if (tid < TI_) {
        int k = tid;
        float prod = 1.f;
#pragma unroll
        for (int l = 0; l < TO_; ++l) {
            float w = ex_s[l][k];
            if (k == TI_ - 1) w = (float)((double)w / s10_s[l]);
            prod *= w;
            ex_s[l][k] = prod;
        }
    }
    __syncthreads();

    // ---- phase 6: cn[l][d] = sum_k cumw*enc ; out = concat([cn, att]) ----
    if (tid < TO_ * H_) {
        int l = tid / H_, d = tid % H_;
        float cn = 0.f;
#pragma unroll
        for (int k = 0; k < TI_; ++k) cn += ex_s[l][k] * enc_s[k][d];
        float* o = out + (size_t)(b * TO_ + l) * (2 * H_);
        o[d]      = cn;
        o[H_ + d] = att_s[l][d];
    }
}

extern "C" void kernel_launch(void* const* d_in, const int* in_sizes, int n_in,
                              void* d_out, int out_size, void* d_ws, size_t ws_size,
                              hipStream_t stream) {
    const float* x    = (const float*)d_in[0];  // [15,10,512]
    const float* h0   = (const float*)d_in[1];  // [1,15,4]
    const float* c0   = (const float*)d_in[2];  // [1,15,4]
    const float* enc  = (const float*)d_in[3];  // [15,10,4]
    const float* W_ih = (const float*)d_in[4];  // [16,512]
    const float* W_hh = (const float*)d_in[5];  // [16,4]
    const float* b_ih = (const float*)d_in[6];  // [16]
    const float* b_hh = (const float*)d_in[7];  // [16]
    float*       out  = (float*)d_out;          // [15,10,8]

    fused_kernel<<<B_, 256, 0, stream>>>(x, h0, c0, enc, W_ih, W_hh, b_ih, b_hh, out);
}

// Round 4
// 12.867 us; speedup vs baseline: 1.8202x; 1.3028x over previous
//
#include <hip/hip_runtime.h>
#include <math.h>

// Problem constants (hardcoded in reference)
#define B_  15
#define TO_ 10   // T_OUT
#define TI_ 10   // T_IN
#define H_  4
#define G_  16   // 4*H
#define D_  512

// ---------------------------------------------------------------------------
// ONE kernel, ONE block per batch element, 1024 threads = 16 waves.
// Phase 1: wave g owns gate-row g of W_ih (pinned in 2 float4 regs), loops
// over the 10 x-rows with full-wave coalesced loads + shfl_xor reduction.
// 4 waves/SIMD gives TLP to hide HBM latency (round-3 version had 1/SIMD).
// Serial tail (LSTM scan + buggy attention) unchanged from round 3.
// ---------------------------------------------------------------------------
__global__ void __launch_bounds__(1024) fused_kernel(
        const float* __restrict__ x,     // [B,TO,D]
        const float* __restrict__ h0,    // [1,B,H]
        const float* __restrict__ c0,    // [1,B,H]
        const float* __restrict__ enc,   // [B,TI,H]
        const float* __restrict__ Wih,   // [G,D]
        const float* __restrict__ Whh,   // [G,H]
        const float* __restrict__ b_ih,  // [G]
        const float* __restrict__ b_hh,  // [G]
        float* __restrict__ out) {       // [B,TO,2H]
    const int b    = blockIdx.x;
    const int tid  = threadIdx.x;
    const int wave = tid >> 6;   // 0..15 == gate index g
    const int lane = tid & 63;

    __shared__ float  xg_s[TO_][G_];
    __shared__ float  att_s[TO_][H_];
    __shared__ float  enc_s[TI_][H_];
    __shared__ float  ex_s[TO_][TI_];
    __shared__ double s10_s[TO_];

    // enc staging issued at the very top (overlaps phase-1 loads); covered
    // by the phase-1 barrier before first use in phase 3.
    if (wave == 1 && lane < TI_ * H_)
        ((float*)enc_s)[lane] = enc[b * TI_ * H_ + lane];

    // Wave 0 prefetches LSTM params into registers.
    float wv0 = 0.f, wv1 = 0.f, wv2 = 0.f, wv3 = 0.f, hreg = 0.f, creg = 0.f;
    if (wave == 0) {
        int g = lane & 15, j = lane & 3;
        wv0  = Whh[g * 4 + 0];
        wv1  = Whh[g * 4 + 1];
        wv2  = Whh[g * 4 + 2];
        wv3  = Whh[g * 4 + 3];
        hreg = h0[b * H_ + j];
        creg = c0[b * H_ + j];
    }

    // ---- phase 1: xg[t][g] = x[b,t,:]·Wih[g,:] + b_ih[g] + b_hh[g] ----
    {
        const int g = wave;
        const float4* Wf4 = (const float4*)Wih;
        const float4* Xf4 = (const float4*)x;
        // pin W row g: lane covers 8 floats = 2 float4
        float4 w0 = Wf4[g * (D_ / 4) + lane * 2 + 0];
        float4 w1 = Wf4[g * (D_ / 4) + lane * 2 + 1];
        float  bsum = b_ih[g] + b_hh[g];
#pragma unroll
        for (int t = 0; t < TO_; ++t) {
            const float4* xr = Xf4 + (size_t)(b * TO_ + t) * (D_ / 4);
            float4 a0 = xr[lane * 2 + 0];
            float4 a1 = xr[lane * 2 + 1];
            float s = a0.x * w0.x + a0.y * w0.y + a0.z * w0.z + a0.w * w0.w
                    + a1.x * w1.x + a1.y * w1.y + a1.z * w1.z + a1.w * w1.w;
            s += __shfl_xor(s, 1);
            s += __shfl_xor(s, 2);
            s += __shfl_xor(s, 4);
            s += __shfl_xor(s, 8);
            s += __shfl_xor(s, 16);
            s += __shfl_xor(s, 32);
            if (lane == 0) xg_s[t][g] = s + bsum;
        }
    }
    __syncthreads();

    // ---- phase 2: wave 0 runs the LSTM scan (shuffle-only, no barriers) ----
    if (wave == 0) {
        int g = lane & 15, j = lane & 3;
        // uniform activation: a=2 -> tanh(v)=2/(1+e^-2v)-1 ; a=1 -> sigmoid
        float a   = (g >= 8 && g < 12) ? 2.f : 1.f;
        float am1 = a - 1.f;
        for (int t = 0; t < TO_; ++t) {
            float v = xg_s[t][g];
            v += __shfl(hreg, 0) * wv0 + __shfl(hreg, 1) * wv1 +
                 __shfl(hreg, 2) * wv2 + __shfl(hreg, 3) * wv3;
            float act = a / (1.f + __expf(-a * v)) - am1;
            float ai = __shfl(act, j),     af = __shfl(act, j + 4),
                  ag = __shfl(act, j + 8), ao = __shfl(act, j + 12);
            creg = af * creg + ai * ag;
            float th = 2.f / (1.f + __expf(-2.f * creg)) - 1.f;
            hreg = ao * th;
            if (lane < 4) att_s[t][lane] = hreg;
        }
    }
    __syncthreads();

    // ---- phase 3: ex[l][k] = exp(<att[l], enc[k]>) ----
    if (tid < TO_ * TI_) {
        int l = tid / TI_, k = tid % TI_;
        float d = 0.f;
#pragma unroll
        for (int j = 0; j < H_; ++j) d += att_s[l][j] * enc_s[k][j];
        ex_s[l][k] = __expf(d);
    }
    __syncthreads();

    // ---- phase 4: row sums -> s^10 in double (s^10 overflows fp32) ----
    if (tid < TO_) {
        float s = 0.f;
#pragma unroll
        for (int k = 0; k < TI_; ++k) s += ex_s[tid][k];
        double sd = (double)s, p = 1.0;
#pragma unroll
        for (int q = 0; q < TI_; ++q) p *= sd;
        s10_s[tid] = p;
    }
    __syncthreads();

    // ---- phase 5: cumprod over l per column k; faithful bug: only the last
    //      key column is divided by s^TI_, folded into the cumprod.
    if (tid < TI_) {
        int k = tid;
        float prod = 1.f;
#pragma unroll
        for (int l = 0; l < TO_; ++l) {
            float w = ex_s[l][k];
            if (k == TI_ - 1) w = (float)((double)w / s10_s[l]);
            prod *= w;
            ex_s[l][k] = prod;
        }
    }
    __syncthreads();

    // ---- phase 6: cn[l][d] = sum_k cumw*enc ; out = concat([cn, att]) ----
    if (tid < TO_ * H_) {
        int l = tid / H_, d = tid % H_;
        float cn = 0.f;
#pragma unroll
        for (int k = 0; k < TI_; ++k) cn += ex_s[l][k] * enc_s[k][d];
        float* o = out + (size_t)(b * TO_ + l) * (2 * H_);
        o[d]      = cn;
        o[H_ + d] = att_s[l][d];
    }
}

extern "C" void kernel_launch(void* const* d_in, const int* in_sizes, int n_in,
                              void* d_out, int out_size, void* d_ws, size_t ws_size,
                              hipStream_t stream) {
    const float* x    = (const float*)d_in[0];  // [15,10,512]
    const float* h0   = (const float*)d_in[1];  // [1,15,4]
    const float* c0   = (const float*)d_in[2];  // [1,15,4]
    const float* enc  = (const float*)d_in[3];  // [15,10,4]
    const float* W_ih = (const float*)d_in[4];  // [16,512]
    const float* W_hh = (const float*)d_in[5];  // [16,4]
    const float* b_ih = (const float*)d_in[6];  // [16]
    const float* b_hh = (const float*)d_in[7];  // [16]
    float*       out  = (float*)d_out;          // [15,10,8]

    fused_kernel<<<B_, 1024, 0, stream>>>(x, h0, c0, enc, W_ih, W_hh, b_ih, b_hh, out);
}

// Round 5
// 12.745 us; speedup vs baseline: 1.8376x; 1.0096x over previous
//
#include <hip/hip_runtime.h>
#include <math.h>

// Problem constants (hardcoded in reference)
#define B_  15
#define TO_ 10   // T_OUT
#define TI_ 10   // T_IN
#define H_  4
#define G_  16   // 4*H
#define D_  512

// ---------------------------------------------------------------------------
// ONE kernel, ONE block per batch element, 1024 threads = 16 waves.
// Phase 1 (all 16 waves): wave g owns W_ih row g in registers, loops over the
// 10 x-rows with coalesced full-wave loads + shfl_xor reduce.  ONE barrier.
// Everything after (LSTM scan + buggy attention tail) runs entirely in wave 0
// with ZERO further barriers: within a single wave, LDS write->read ordering
// is guaranteed (compiler-inserted lgkmcnt waits), so no __syncthreads needed.
// ---------------------------------------------------------------------------
__global__ void __launch_bounds__(1024) fused_kernel(
        const float* __restrict__ x,     // [B,TO,D]
        const float* __restrict__ h0,    // [1,B,H]
        const float* __restrict__ c0,    // [1,B,H]
        const float* __restrict__ enc,   // [B,TI,H]
        const float* __restrict__ Wih,   // [G,D]
        const float* __restrict__ Whh,   // [G,H]
        const float* __restrict__ b_ih,  // [G]
        const float* __restrict__ b_hh,  // [G]
        float* __restrict__ out) {       // [B,TO,2H]
    const int b    = blockIdx.x;
    const int tid  = threadIdx.x;
    const int wave = tid >> 6;   // 0..15 == gate index g for phase 1
    const int lane = tid & 63;

    __shared__ float  xg_s[TO_][G_];
    __shared__ float  att_s[TO_][H_];
    __shared__ float  enc_s[TI_][H_];
    __shared__ float  ex_s[TO_][TI_];
    __shared__ double s10_s[TO_];

    // enc staging issued at the very top (overlaps phase-1 loads); wave 1
    // writes it, wave 0 reads it only after the phase-1 barrier.
    if (wave == 1 && lane < TI_ * H_)
        ((float*)enc_s)[lane] = enc[b * TI_ * H_ + lane];

    // Wave 0 prefetches LSTM params into registers (latency hides under
    // phase-1 work).
    float wv0 = 0.f, wv1 = 0.f, wv2 = 0.f, wv3 = 0.f, hreg = 0.f, creg = 0.f;
    if (wave == 0) {
        int g = lane & 15, j = lane & 3;
        wv0  = Whh[g * 4 + 0];
        wv1  = Whh[g * 4 + 1];
        wv2  = Whh[g * 4 + 2];
        wv3  = Whh[g * 4 + 3];
        hreg = h0[b * H_ + j];
        creg = c0[b * H_ + j];
    }

    // ---- phase 1: xg[t][g] = x[b,t,:]·Wih[g,:] + b_ih[g] + b_hh[g] ----
    {
        const int g = wave;
        const float4* Wf4 = (const float4*)Wih;
        const float4* Xf4 = (const float4*)x;
        float4 w0 = Wf4[g * (D_ / 4) + lane * 2 + 0];
        float4 w1 = Wf4[g * (D_ / 4) + lane * 2 + 1];
        float  bsum = b_ih[g] + b_hh[g];
#pragma unroll
        for (int t = 0; t < TO_; ++t) {
            const float4* xr = Xf4 + (size_t)(b * TO_ + t) * (D_ / 4);
            float4 a0 = xr[lane * 2 + 0];
            float4 a1 = xr[lane * 2 + 1];
            float s = a0.x * w0.x + a0.y * w0.y + a0.z * w0.z + a0.w * w0.w
                    + a1.x * w1.x + a1.y * w1.y + a1.z * w1.z + a1.w * w1.w;
            s += __shfl_xor(s, 1);
            s += __shfl_xor(s, 2);
            s += __shfl_xor(s, 4);
            s += __shfl_xor(s, 8);
            s += __shfl_xor(s, 16);
            s += __shfl_xor(s, 32);
            if (lane == 0) xg_s[t][g] = s + bsum;
        }
    }
    __syncthreads();   // the ONLY barrier

    // ======================= wave 0 does everything below ==================
    if (wave == 0) {
        // ---- phase 2: LSTM scan (shuffle-only) ----
        {
            int g = lane & 15, j = lane & 3;
            // uniform activation: a=2 -> tanh ; a=1 -> sigmoid
            float a   = (g >= 8 && g < 12) ? 2.f : 1.f;
            float am1 = a - 1.f;
            for (int t = 0; t < TO_; ++t) {
                float v = xg_s[t][g];
                v += __shfl(hreg, 0) * wv0 + __shfl(hreg, 1) * wv1 +
                     __shfl(hreg, 2) * wv2 + __shfl(hreg, 3) * wv3;
                float act = a / (1.f + __expf(-a * v)) - am1;
                float ai = __shfl(act, j),     af = __shfl(act, j + 4),
                      ag = __shfl(act, j + 8), ao = __shfl(act, j + 12);
                creg = af * creg + ai * ag;
                float th = 2.f / (1.f + __expf(-2.f * creg)) - 1.f;
                hreg = ao * th;
                if (lane < 4) att_s[t][lane] = hreg;
            }
        }

        // ---- phase 3: ex[l][k] = exp(<att[l], enc[k]>)  (100 vals, 2/lane)
#pragma unroll
        for (int rep = 0; rep < 2; ++rep) {
            int i = lane + rep * 64;
            if (i < TO_ * TI_) {
                int l = i / TI_, k = i % TI_;
                float d = 0.f;
#pragma unroll
                for (int j = 0; j < H_; ++j) d += att_s[l][j] * enc_s[k][j];
                ex_s[l][k] = __expf(d);
            }
        }

        // ---- phase 4: row sums -> s^10 in double (s^10 overflows fp32) ----
        if (lane < TO_) {
            float s = 0.f;
#pragma unroll
            for (int k = 0; k < TI_; ++k) s += ex_s[lane][k];
            double sd = (double)s, p = 1.0;
#pragma unroll
            for (int q = 0; q < TI_; ++q) p *= sd;
            s10_s[lane] = p;
        }

        // ---- phase 5: cumprod over l per column k; faithful bug: only the
        //      last key column is divided by s^TI_, folded into the cumprod.
        if (lane < TI_) {
            int k = lane;
            float prod = 1.f;
#pragma unroll
            for (int l = 0; l < TO_; ++l) {
                float w = ex_s[l][k];
                if (k == TI_ - 1) w = (float)((double)w / s10_s[l]);
                prod *= w;
                ex_s[l][k] = prod;
            }
        }

        // ---- phase 6: cn[l][d] = sum_k cumw*enc ; out = concat([cn,att]) ----
        if (lane < TO_ * H_) {
            int l = lane / H_, d = lane % H_;
            float cn = 0.f;
#pragma unroll
            for (int k = 0; k < TI_; ++k) cn += ex_s[l][k] * enc_s[k][d];
            float* o = out + (size_t)(b * TO_ + l) * (2 * H_);
            o[d]      = cn;
            o[H_ + d] = att_s[l][d];
        }
    }
}

extern "C" void kernel_launch(void* const* d_in, const int* in_sizes, int n_in,
                              void* d_out, int out_size, void* d_ws, size_t ws_size,
                              hipStream_t stream) {
    const float* x    = (const float*)d_in[0];  // [15,10,512]
    const float* h0   = (const float*)d_in[1];  // [1,15,4]
    const float* c0   = (const float*)d_in[2];  // [1,15,4]
    const float* enc  = (const float*)d_in[3];  // [15,10,4]
    const float* W_ih = (const float*)d_in[4];  // [16,512]
    const float* W_hh = (const float*)d_in[5];  // [16,4]
    const float* b_ih = (const float*)d_in[6];  // [16]
    const float* b_hh = (const float*)d_in[7];  // [16]
    float*       out  = (float*)d_out;          // [15,10,8]

    fused_kernel<<<B_, 1024, 0, stream>>>(x, h0, c0, enc, W_ih, W_hh, b_ih, b_hh, out);
}